// Round 2
// baseline (84.810 us; speedup 1.0000x reference)
//
#include <hip/hip_runtime.h>

// QuantumVQCHead: a = tanh(h @ W_pre^T + b_pre) * pi/2 ; 8-qubit VQC (RY embed,
// RX/RY/RZ layer, CNOT ring) ; 24 Pauli expectations ; L2-normalize.
// All inputs/outputs are FLOAT32 (per reference dtypes).
//
// Analytic reduction: state before the CNOT ring is a product state; the CNOT
// ring is Clifford, so every observable back-propagates to a product of
// per-qubit factors (verified by stabilizer conjugation):
//   Zq = |a|^2-|b|^2, Xq = 2Re(conj(a)b), Yq = 2Im(conj(a)b) per qubit, then
//   X[w]=Xw*X{w+1} (w<7), X[7]=X7*X0*X1
//   Y[0]=X0*Y1*prod_{2..7}Z ; Y[w]=Yw*X{w+1}*prod_{0..w-1}Z (1<=w<=6)
//   Y[7]=-Y7*Y0*Y1*prod_{2..6}Z
//   Z[0]=prod_{1..7}Z ; Z[w]=prod_{0..w}Z
// so the kernel is a 16384x512 @ 512x8 f32 GEMV + tiny epilogue.

// Per-output factor masks: bits 0..7 -> Xq, 8..15 -> Yq, 16..23 -> Zq, 31 -> negate.
__device__ const unsigned int OMASK[24] = {
  0x00000003u, // X0
  0x00FC0201u, // Y0
  0x00FE0000u, // Z0
  0x00000006u, // X1
  0x00010204u, // Y1
  0x00030000u, // Z1
  0x0000000Cu, // X2
  0x00030408u, // Y2
  0x00070000u, // Z2
  0x00000018u, // X3
  0x00070810u, // Y3
  0x000F0000u, // Z3
  0x00000030u, // X4
  0x000F1020u, // Y4
  0x001F0000u, // Z4
  0x00000060u, // X5
  0x001F2040u, // Y5
  0x003F0000u, // Z5
  0x000000C0u, // X6
  0x003F4080u, // Y6
  0x007F0000u, // Z6
  0x00000083u, // X7
  0x807C8300u, // Y7 (negated)
  0x00FF0000u  // Z7
};

__global__ __launch_bounds__(256) void vqc_kernel(
    const float* __restrict__ h,    // [B,512] f32
    const float* __restrict__ Wp,   // [8,512] f32
    const float* __restrict__ bp,   // [8] f32
    const float* __restrict__ wt,   // [1,8,3] f32
    float* __restrict__ out,        // [B,24] f32
    int B)
{
    const int lane  = threadIdx.x & 63;
    const int wave  = (blockIdx.x * blockDim.x + threadIdx.x) >> 6;
    const int nwv   = (gridDim.x * blockDim.x) >> 6;
    const int u     = lane >> 3;             // qubit index for this lane group

    // ---- per-wave constants: W slice (registers), bias, per-qubit matrix M ----
    // lane covers columns [lane*8, lane*8+8)
    const float4* W4 = (const float4*)Wp;
    float wf[8][8];
    #pragma unroll
    for (int q = 0; q < 8; ++q) {
        float4 v0 = W4[q * 128 + lane * 2 + 0];
        float4 v1 = W4[q * 128 + lane * 2 + 1];
        wf[q][0] = v0.x; wf[q][1] = v0.y; wf[q][2] = v0.z; wf[q][3] = v0.w;
        wf[q][4] = v1.x; wf[q][5] = v1.y; wf[q][6] = v1.z; wf[q][7] = v1.w;
    }
    const float bias = bp[u];

    // M = RZ(t2) * RY(t1) * RX(t0) for qubit u (batch-constant, complex 2x2)
    float t0 = wt[u * 3 + 0] * 0.5f;
    float t1 = wt[u * 3 + 1] * 0.5f;
    float t2 = wt[u * 3 + 2] * 0.5f;
    float s0, c0, s1, c1, sz, cz;
    __sincosf(t0, &s0, &c0);
    __sincosf(t1, &s1, &c1);
    __sincosf(t2, &sz, &cz);
    // RY(t1)*RX(t0):
    const float N00r =  c1 * c0, N00i =  s1 * s0;
    const float N01r = -s1 * c0, N01i = -c1 * s0;
    const float N10r =  s1 * c0, N10i = -c1 * s0;
    const float N11r =  c1 * c0, N11i = -s1 * s0;
    // row0 *= exp(-i t2), row1 *= exp(+i t2):
    const float M00r = cz * N00r + sz * N00i, M00i = cz * N00i - sz * N00r;
    const float M01r = cz * N01r + sz * N01i, M01i = cz * N01i - sz * N01r;
    const float M10r = cz * N10r - sz * N10i, M10i = cz * N10i + sz * N10r;
    const float M11r = cz * N11r - sz * N11i, M11i = cz * N11i + sz * N11r;

    const unsigned int omask = OMASK[lane < 24 ? lane : 0];

    const float4* H4 = (const float4*)h;
    const int R = (B + nwv - 1) / nwv;
    const int row0 = wave * R;

    for (int r = 0; r < R; ++r) {
        const int row = row0 + r;
        if (row >= B) break;

        // ---- GEMV: 64 lanes x 8 cols each, f32 accumulate ----
        float4 h0 = H4[row * 128 + lane * 2 + 0];
        float4 h1 = H4[row * 128 + lane * 2 + 1];
        float hf[8] = { h0.x, h0.y, h0.z, h0.w, h1.x, h1.y, h1.z, h1.w };
        float acc[8];
        #pragma unroll
        for (int q = 0; q < 8; ++q) {
            float a = 0.f;
            #pragma unroll
            for (int j = 0; j < 8; ++j) a = fmaf(wf[q][j], hf[j], a);
            acc[q] = a;
        }
        // phase 1: reduce across lane bits 3..5 (keeps per-(lane&7) partials)
        #pragma unroll
        for (int q = 0; q < 8; ++q) {
            acc[q] += __shfl_xor(acc[q], 8);
            acc[q] += __shfl_xor(acc[q], 16);
            acc[q] += __shfl_xor(acc[q], 32);
        }
        // phase 2: each lane group picks its qubit, reduce across bits 0..2
        float v = acc[0];
        #pragma unroll
        for (int q = 1; q < 8; ++q) v = (u == q) ? acc[q] : v;
        v += __shfl_xor(v, 1);
        v += __shfl_xor(v, 2);
        v += __shfl_xor(v, 4);

        // ---- angle -> per-qubit single-qubit state ----
        float a = v + bias;
        a = fminf(fmaxf(a, -10.f), 10.f);
        float e = __expf(a + a);
        float th = (e - 1.f) / (e + 1.f);          // tanh(a)
        float phi = th * 0.78539816339744831f;     // tanh(a)*(pi/2) / 2
        float ss, cc;
        __sincosf(phi, &ss, &cc);
        float ar = M00r * cc + M01r * ss, ai = M00i * cc + M01i * ss;
        float br = M10r * cc + M11r * ss, bi = M10i * cc + M11i * ss;
        float Zv = (ar * ar + ai * ai) - (br * br + bi * bi);
        float Xv = 2.f * (ar * br + ai * bi);
        float Yv = 2.f * (ar * bi - ai * br);

        // ---- broadcast per-qubit factors to all lanes ----
        float Xs[8], Ys[8], Zs[8];
        #pragma unroll
        for (int q = 0; q < 8; ++q) {
            Xs[q] = __shfl(Xv, q * 8);
            Ys[q] = __shfl(Yv, q * 8);
            Zs[q] = __shfl(Zv, q * 8);
        }

        // ---- lane j (<24) computes output j as masked product ----
        float val = 1.f;
        #pragma unroll
        for (int q = 0; q < 8; ++q) {
            float f = 1.f;
            if (omask & (1u       << q)) f = Xs[q];
            if (omask & (0x100u   << q)) f = Ys[q];
            if (omask & (0x10000u << q)) f = Zs[q];
            val *= f;
        }
        if (omask & 0x80000000u) val = -val;

        // ---- L2 norm over the 24 outputs (lanes >=24 contribute 0) ----
        float sq = (lane < 24) ? val * val : 0.f;
        sq += __shfl_xor(sq, 1);
        sq += __shfl_xor(sq, 2);
        sq += __shfl_xor(sq, 4);
        sq += __shfl_xor(sq, 8);
        sq += __shfl_xor(sq, 16);
        float nrm = fmaxf(sqrtf(sq), 1e-12f);
        float o = val / nrm;

        if (lane < 24) out[row * 24 + lane] = o;
    }
}

extern "C" void kernel_launch(void* const* d_in, const int* in_sizes, int n_in,
                              void* d_out, int out_size, void* d_ws, size_t ws_size,
                              hipStream_t stream) {
    const float* h  = (const float*)d_in[0];
    const float* Wp = (const float*)d_in[1];
    const float* bp = (const float*)d_in[2];
    const float* wt = (const float*)d_in[3];
    float* out = (float*)d_out;

    const int B = in_sizes[0] / 512;     // 16384
    const int nblk = 1024;               // 4096 waves -> 4 rows/wave at B=16384
    vqc_kernel<<<nblk, 256, 0, stream>>>(h, Wp, bp, wt, out, B);
}

// Round 3
// 83.452 us; speedup vs baseline: 1.0163x; 1.0163x over previous
//
#include <hip/hip_runtime.h>

// QuantumVQCHead, two-stage:
//   Stage 1: a = h @ W_pre^T   (16384x512 @ 512x8 f32 GEMV) -> d_ws
//   Stage 2: per-row scalar epilogue: tanh/clip angle, single-qubit states,
//            Pauli-propagated observables through the CNOT ring, L2-normalize.
//
// Observable algebra (verified by stabilizer conjugation through the ring
// C70*C67*...*C01, in that operator order):
//   X[w] = Xw*X{w+1} (w<7),  X[7] = X7*X0*X1
//   Y[0] = X0*Y1*Z2..Z7 ; Y[w] = Yw*X{w+1}*Z0..Z{w-1} (1<=w<=6)
//   Y[7] = -Y7*Y0*Y1*Z2..Z6
//   Z[0] = Z1..Z7 ; Z[w>=1] = Z0..Zw
// with per-qubit Bloch components X,Y,Z of |chi> = RZ RY RX RY(a)|0>.

__global__ __launch_bounds__(256) void vqc_gemv(
    const float* __restrict__ h,    // [B,512]
    const float* __restrict__ Wp,   // [8,512]
    float* __restrict__ aw,         // [B,8] raw dots (no bias)
    int B)
{
    const int lane = threadIdx.x & 63;
    const int wave = (blockIdx.x * blockDim.x + threadIdx.x) >> 6;
    const int nwv  = (gridDim.x * blockDim.x) >> 6;

    // lane covers columns [lane*8, lane*8+8)
    const float4* W4 = (const float4*)Wp;
    float wf[8][8];
    #pragma unroll
    for (int q = 0; q < 8; ++q) {
        float4 v0 = W4[q * 128 + lane * 2 + 0];
        float4 v1 = W4[q * 128 + lane * 2 + 1];
        wf[q][0] = v0.x; wf[q][1] = v0.y; wf[q][2] = v0.z; wf[q][3] = v0.w;
        wf[q][4] = v1.x; wf[q][5] = v1.y; wf[q][6] = v1.z; wf[q][7] = v1.w;
    }

    const int b3 = (lane >> 3) & 1, b4 = (lane >> 4) & 1, b5 = (lane >> 5) & 1;
    const float4* H4 = (const float4*)h;

    const int row0 = wave * 2;
    if (row0 >= B) return;

    // hoist both rows' loads
    float4 h00 = H4[row0 * 128 + lane * 2 + 0];
    float4 h01 = H4[row0 * 128 + lane * 2 + 1];
    int row1 = row0 + 1;
    float4 h10 = H4[(row1 < B ? row1 : row0) * 128 + lane * 2 + 0];
    float4 h11 = H4[(row1 < B ? row1 : row0) * 128 + lane * 2 + 1];

    float hf0[8] = { h00.x, h00.y, h00.z, h00.w, h01.x, h01.y, h01.z, h01.w };
    float hf1[8] = { h10.x, h10.y, h10.z, h10.w, h11.x, h11.y, h11.z, h11.w };

    float acc0[8], acc1[8];
    #pragma unroll
    for (int q = 0; q < 8; ++q) {
        float a0 = 0.f, a1 = 0.f;
        #pragma unroll
        for (int j = 0; j < 8; ++j) {
            a0 = fmaf(wf[q][j], hf0[j], a0);
            a1 = fmaf(wf[q][j], hf1[j], a1);
        }
        acc0[q] = a0; acc1[q] = a1;
    }

    // log-halving reduce: distribute 8 accs over lane bits 3..5 (10 shuffles/row)
    // step A (xor 8): keep qubits with bit0 == b3
    float n0[4], n1[4];
    #pragma unroll
    for (int j = 0; j < 4; ++j) {
        float k0 = b3 ? acc0[1 + 2*j] : acc0[0 + 2*j];
        float s0 = b3 ? acc0[0 + 2*j] : acc0[1 + 2*j];
        float k1 = b3 ? acc1[1 + 2*j] : acc1[0 + 2*j];
        float s1 = b3 ? acc1[0 + 2*j] : acc1[1 + 2*j];
        n0[j] = k0 + __shfl_xor(s0, 8);
        n1[j] = k1 + __shfl_xor(s1, 8);
    }
    // step B (xor 16): keep bit1 == b4
    float m0[2], m1[2];
    #pragma unroll
    for (int i = 0; i < 2; ++i) {
        float k0 = b4 ? n0[1 + 2*i] : n0[0 + 2*i];
        float s0 = b4 ? n0[0 + 2*i] : n0[1 + 2*i];
        float k1 = b4 ? n1[1 + 2*i] : n1[0 + 2*i];
        float s1 = b4 ? n1[0 + 2*i] : n1[1 + 2*i];
        m0[i] = k0 + __shfl_xor(s0, 16);
        m1[i] = k1 + __shfl_xor(s1, 16);
    }
    // step C (xor 32): keep bit2 == b5
    float v0, v1;
    {
        float k0 = b5 ? m0[1] : m0[0];
        float s0 = b5 ? m0[0] : m0[1];
        float k1 = b5 ? m1[1] : m1[0];
        float s1 = b5 ? m1[0] : m1[1];
        v0 = k0 + __shfl_xor(s0, 32);
        v1 = k1 + __shfl_xor(s1, 32);
    }
    // butterfly over bits 0..2: full 512-col sum; qubit index = lane>>3
    v0 += __shfl_xor(v0, 1); v1 += __shfl_xor(v1, 1);
    v0 += __shfl_xor(v0, 2); v1 += __shfl_xor(v1, 2);
    v0 += __shfl_xor(v0, 4); v1 += __shfl_xor(v1, 4);

    if ((lane & 7) == 0) {
        int q = lane >> 3;
        aw[row0 * 8 + q] = v0;
        if (row1 < B) aw[row1 * 8 + q] = v1;
    }
}

__global__ __launch_bounds__(256) void vqc_epilogue(
    const float* __restrict__ aw,   // [B,8]
    const float* __restrict__ bp,   // [8]
    const float* __restrict__ wt,   // [1,8,3]
    float* __restrict__ out,        // [B,24]
    int B)
{
    const int row = blockIdx.x * blockDim.x + threadIdx.x;
    if (row >= B) return;

    const float4* A4 = (const float4*)aw;
    float4 a0 = A4[row * 2 + 0];
    float4 a1 = A4[row * 2 + 1];
    float av[8] = { a0.x, a0.y, a0.z, a0.w, a1.x, a1.y, a1.z, a1.w };

    float X[8], Y[8], Z[8];
    #pragma unroll
    for (int q = 0; q < 8; ++q) {
        // batch-constant single-qubit matrix M = RZ(t2)RY(t1)RX(t0)
        float t0 = wt[q * 3 + 0] * 0.5f;
        float t1 = wt[q * 3 + 1] * 0.5f;
        float t2 = wt[q * 3 + 2] * 0.5f;
        float s0, c0, s1, c1, sz, cz;
        __sincosf(t0, &s0, &c0);
        __sincosf(t1, &s1, &c1);
        __sincosf(t2, &sz, &cz);
        float N00r =  c1 * c0, N00i =  s1 * s0;
        float N01r = -s1 * c0, N01i = -c1 * s0;
        float N10r =  s1 * c0, N10i = -c1 * s0;
        float N11r =  c1 * c0, N11i = -s1 * s0;
        float M00r = cz * N00r + sz * N00i, M00i = cz * N00i - sz * N00r;
        float M01r = cz * N01r + sz * N01i, M01i = cz * N01i - sz * N01r;
        float M10r = cz * N10r - sz * N10i, M10i = cz * N10i + sz * N10r;
        float M11r = cz * N11r - sz * N11i, M11i = cz * N11i + sz * N11r;

        float a = av[q] + bp[q];
        a = fminf(fmaxf(a, -15.f), 15.f);
        float e = __expf(a + a);
        float th = (e - 1.f) / (e + 1.f);          // tanh(a)
        float phi = th * 0.78539816339744831f;     // tanh(a)*(pi/2)/2
        float ss, cc;
        __sincosf(phi, &ss, &cc);
        float ar = M00r * cc + M01r * ss, ai = M00i * cc + M01i * ss;
        float br = M10r * cc + M11r * ss, bi = M10i * cc + M11i * ss;
        Z[q] = (ar * ar + ai * ai) - (br * br + bi * bi);
        X[q] = 2.f * (ar * br + ai * bi);
        Y[q] = 2.f * (ar * bi - ai * br);
    }

    // prefix P[w] = Z0..Zw ; suffix T[w] = Zw..Z7
    float P[8], T[8];
    P[0] = Z[0];
    #pragma unroll
    for (int w = 1; w < 8; ++w) P[w] = P[w - 1] * Z[w];
    T[7] = Z[7];
    #pragma unroll
    for (int w = 6; w >= 0; --w) T[w] = Z[w] * T[w + 1];
    float Z2to6 = Z[2] * Z[3] * Z[4] * Z[5] * Z[6];

    float o[24];
    #pragma unroll
    for (int w = 0; w < 7; ++w) o[3 * w] = X[w] * X[w + 1];
    o[21] = X[7] * X[0] * X[1];
    o[1] = X[0] * Y[1] * T[2];
    #pragma unroll
    for (int w = 1; w < 7; ++w) o[3 * w + 1] = Y[w] * X[w + 1] * P[w - 1];
    o[22] = -Y[7] * Y[0] * Y[1] * Z2to6;
    o[2] = T[1];
    #pragma unroll
    for (int w = 1; w < 8; ++w) o[3 * w + 2] = P[w];

    float sq = 0.f;
    #pragma unroll
    for (int j = 0; j < 24; ++j) sq = fmaf(o[j], o[j], sq);
    float inv = 1.f / fmaxf(sqrtf(sq), 1e-12f);

    float4* O4 = (float4*)(out + row * 24);
    #pragma unroll
    for (int j = 0; j < 6; ++j) {
        float4 vv = { o[4 * j] * inv, o[4 * j + 1] * inv,
                      o[4 * j + 2] * inv, o[4 * j + 3] * inv };
        O4[j] = vv;
    }
}

extern "C" void kernel_launch(void* const* d_in, const int* in_sizes, int n_in,
                              void* d_out, int out_size, void* d_ws, size_t ws_size,
                              hipStream_t stream) {
    const float* h  = (const float*)d_in[0];
    const float* Wp = (const float*)d_in[1];
    const float* bp = (const float*)d_in[2];
    const float* wt = (const float*)d_in[3];
    float* out = (float*)d_out;
    float* aw  = (float*)d_ws;            // [B,8] scratch

    const int B = in_sizes[0] / 512;      // 16384
    const int nblk1 = (B + 511) / 512;    // 2 rows per wave, 4 waves per block
    vqc_gemv<<<nblk1 * 128, 256, 0, stream>>>(h, Wp, aw, B);
    vqc_epilogue<<<(B + 255) / 256, 256, 0, stream>>>(aw, bp, wt, out, B);
}